// Round 11
// baseline (779.577 us; speedup 1.0000x reference)
//
#include <hip/hip_runtime.h>
#include <cstdint>
#include <cstddef>

typedef short bf16x8 __attribute__((ext_vector_type(8)));
typedef float f32x4  __attribute__((ext_vector_type(4)));

// ---- bf16 pack/unpack helpers (RNE) ----
static __device__ __forceinline__ unsigned int f2bf_rne(float f) {
    unsigned int u = __float_as_uint(f);
    unsigned int r = 0x7FFFu + ((u >> 16) & 1u);
    return (u + r) >> 16;
}
static __device__ __forceinline__ unsigned int pack_bf2(float lo, float hi) {
    return f2bf_rne(lo) | (f2bf_rne(hi) << 16);
}
static __device__ __forceinline__ float bf_lo(unsigned int w) {
    return __uint_as_float(w << 16);
}
static __device__ __forceinline__ float bf_hi(unsigned int w) {
    return __uint_as_float(w & 0xFFFF0000u);
}

#define BKT_CH 8192    // edges per chunk-block (fits LDS staging: 2x32KB)

// ---------------- CSR build (R6-R8: zero per-edge global atomics) ----------------

__global__ void k_detect64(const unsigned int* ei, int e, int* is64) {
    __shared__ int nonzero;
    if (threadIdx.x == 0) nonzero = 0;
    __syncthreads();
    for (int i = threadIdx.x; i < 4096; i += blockDim.x) {
        size_t k = (size_t)((unsigned long long)i * (unsigned long long)e / 4096ull);
        if (ei[2 * k + 1] != 0u) nonzero = 1;   // racy OR, fine
    }
    __syncthreads();
    if (threadIdx.x == 0) *is64 = nonzero ? 0 : 1;
}

__global__ void k_zero512(int* p) { p[threadIdx.x] = 0; }

__global__ __launch_bounds__(256) void k_hist(const void* ei_raw, int e, const int* is64,
                                              int* __restrict__ bkt_cnt) {
    __shared__ int lcnt[512];
    int t = threadIdx.x;
    for (int j = t; j < 512; j += 256) lcnt[j] = 0;
    __syncthreads();
    int lo = blockIdx.x * BKT_CH;
    int hi = lo + BKT_CH; if (hi > e) hi = e;
    if (*is64) {
        const long long* p = (const long long*)ei_raw;
        for (int i = lo + t; i < hi; i += 256)
            atomicAdd(&lcnt[((int)p[(size_t)e + i]) >> 8], 1);
    } else {
        const int* p = (const int*)ei_raw;
        for (int i = lo + t; i < hi; i += 256)
            atomicAdd(&lcnt[p[(size_t)e + i] >> 8], 1);
    }
    __syncthreads();
    for (int j = t; j < 512; j += 256)
        if (lcnt[j]) atomicAdd(&bkt_cnt[j], lcnt[j]);
}

__global__ __launch_bounds__(512) void k_scan_bkt(const int* __restrict__ bkt_cnt,
                                                  int* __restrict__ bkt_base,
                                                  int* __restrict__ bkt_cursor, int nb) {
    __shared__ int s[512];
    int t = threadIdx.x;
    int v = (t < nb) ? bkt_cnt[t] : 0;
    s[t] = v;
    __syncthreads();
    #pragma unroll
    for (int d = 1; d < 512; d <<= 1) {
        int tmp = (t >= d) ? s[t - d] : 0;
        __syncthreads();
        s[t] += tmp;
        __syncthreads();
    }
    if (t < nb) {
        int b = s[t] - v;
        bkt_base[t]   = b;
        bkt_cursor[t] = b;
    }
    if (t == 511) bkt_base[nb] = s[511];
}

__global__ __launch_bounds__(256) void k_bucket(const void* ei_raw, int e, const int* is64,
                                                int* __restrict__ bkt_cursor,
                                                unsigned int* __restrict__ pout) {
    __shared__ int ldst[BKT_CH];
    __shared__ int lsrc[BKT_CH];
    __shared__ int lcnt[512];
    __shared__ int lbase[512];
    int t = threadIdx.x;
    int lo = blockIdx.x * BKT_CH;
    int hi = lo + BKT_CH; if (hi > e) hi = e;
    int m = hi - lo;
    for (int j = t; j < 512; j += 256) lcnt[j] = 0;
    __syncthreads();
    bool w64 = (*is64 != 0);
    const long long* p64 = (const long long*)ei_raw;
    const int*       p32 = (const int*)ei_raw;
    for (int idx = t; idx < m; idx += 256) {
        size_t i = (size_t)lo + idx;
        int s, d;
        if (w64) { s = (int)p64[i]; d = (int)p64[(size_t)e + i]; }
        else     { s = p32[i];      d = p32[(size_t)e + i]; }
        ldst[idx] = d;
        lsrc[idx] = s;
        atomicAdd(&lcnt[d >> 8], 1);
    }
    __syncthreads();
    for (int j = t; j < 512; j += 256) {
        int c = lcnt[j];
        lbase[j] = c ? atomicAdd(&bkt_cursor[j], c) : 0;
        lcnt[j] = 0;
    }
    __syncthreads();
    for (int idx = t; idx < m; idx += 256) {
        int d = ldst[idx], s = lsrc[idx];
        int b = d >> 8;
        int pos = lbase[b] + atomicAdd(&lcnt[b], 1);
        pout[pos] = ((unsigned int)(d & 255) << 24) | (unsigned int)s;
    }
}

__global__ __launch_bounds__(256) void k_place_deg(const unsigned int* __restrict__ pairs,
                                                   const int* __restrict__ bkt_base,
                                                   int n, int nb,
                                                   int* __restrict__ row_ptr,
                                                   float* __restrict__ dinv,
                                                   int* __restrict__ src_sorted) {
    __shared__ int lcnt[256];
    __shared__ int ls[256];
    __shared__ int lcur[256];
    int b = blockIdx.x;
    int t = threadIdx.x;
    int base = bkt_base[b], end = bkt_base[b + 1];
    lcnt[t] = 0;
    __syncthreads();
    for (int i = base + t; i < end; i += 256)
        atomicAdd(&lcnt[__builtin_nontemporal_load(&pairs[i]) >> 24], 1);
    __syncthreads();
    int v = lcnt[t];
    ls[t] = v;
    __syncthreads();
    #pragma unroll
    for (int d = 1; d < 256; d <<= 1) {
        int tmp = (t >= d) ? ls[t - d] : 0;
        __syncthreads();
        ls[t] += tmp;
        __syncthreads();
    }
    int nodebase = base + ls[t] - v;
    int node = (b << 8) + t;
    if (node < n) {
        row_ptr[node] = nodebase;
        dinv[node] = rsqrtf((float)(v + 1));
    }
    lcur[t] = nodebase;
    __syncthreads();
    for (int i = base + t; i < end; i += 256) {
        unsigned int pr = __builtin_nontemporal_load(&pairs[i]);
        int pos = atomicAdd(&lcur[pr >> 24], 1);
        src_sorted[pos] = (int)(pr & 0x00FFFFFFu);
    }
    if (t == 0 && b == nb - 1) row_ptr[n] = end;
}

// ---------------- Layer-1 GEMM: MFMA bf16 16x16x32 (R10) ----------------
__global__ __launch_bounds__(256) void k_gemm128(const float* __restrict__ A,
                                                 const float* __restrict__ W,
                                                 const float* __restrict__ dinv,
                                                 unsigned int* __restrict__ hsb, int M) {
    __shared__ unsigned int A_lds[64][68];
    __shared__ unsigned int B_lds[16 * 128 * 4];
    int tid = threadIdx.x;
    int w   = tid >> 6;
    int l   = tid & 63;
    int row0 = blockIdx.x * 64;

    for (int idx = tid; idx < 4096; idx += 256) {
        int r = idx >> 6, kp = idx & 63;
        unsigned int pv = 0u;
        int gr = row0 + r;
        if (gr < M) {
            float2 f = *reinterpret_cast<const float2*>(&A[(size_t)gr * 128 + 2 * kp]);
            pv = pack_bf2(f.x, f.y);
        }
        A_lds[r][kp] = pv;
    }
    for (int idx = tid; idx < 8192; idx += 256) {
        int col = idx & 127, kp = idx >> 7;
        float v0 = W[(size_t)(2 * kp) * 128 + col];
        float v1 = W[(size_t)(2 * kp + 1) * 128 + col];
        B_lds[(((kp >> 2) * 128) + col) * 4 + (kp & 3)] = pack_bf2(v0, v1);
    }
    __syncthreads();

    int arow = w * 16 + (l & 15);
    int kq   = (l >> 4);
    f32x4 acc[8];
    #pragma unroll
    for (int nb = 0; nb < 8; ++nb) acc[nb] = (f32x4){0.f, 0.f, 0.f, 0.f};

    #pragma unroll
    for (int k0 = 0; k0 < 4; ++k0) {
        bf16x8 af = *reinterpret_cast<const bf16x8*>(&A_lds[arow][k0 * 16 + kq * 4]);
        #pragma unroll
        for (int nb = 0; nb < 8; ++nb) {
            const unsigned int* bp = &B_lds[(((k0 * 4 + kq) * 128) + nb * 16 + (l & 15)) * 4];
            bf16x8 bf = *reinterpret_cast<const bf16x8*>(bp);
            acc[nb] = __builtin_amdgcn_mfma_f32_16x16x32_bf16(af, bf, acc[nb], 0, 0, 0);
        }
    }

    #pragma unroll
    for (int r = 0; r < 4; ++r) {
        int gr = row0 + w * 16 + (l >> 4) * 4 + r;
        float di = (gr < M) ? dinv[gr] : 0.f;
        #pragma unroll
        for (int nb = 0; nb < 8; ++nb) {
            float fv = acc[nb][r] * di;
            float pv = __shfl_xor(fv, 1);
            if ((l & 1) == 0 && gr < M) {
                hsb[(size_t)gr * 64 + nb * 8 + ((l & 15) >> 1)] = pack_bf2(fv, pv);
            }
        }
    }
}

// ---------------- Layer-2 GEMM: MFMA bf16, A from slice-major h2bs ----------------
// h2bs layout: [slice 0..7][n][8 words] (written by sliced k_agg1).
__global__ __launch_bounds__(256) void k_gemm64(const unsigned int* __restrict__ h2bs,
                                                const float* __restrict__ W,
                                                const float* __restrict__ dinv,
                                                unsigned int* __restrict__ zsb, int M, int n) {
    __shared__ unsigned int A_lds[64][68];
    __shared__ unsigned int B_lds[16 * 64 * 4];
    int tid = threadIdx.x;
    int w   = tid >> 6;
    int l   = tid & 63;
    int row0 = blockIdx.x * 64;

    for (int idx = tid; idx < 4096; idx += 256) {
        int r = idx >> 6, kp = idx & 63;
        int gr = row0 + r;
        A_lds[r][kp] = (gr < M)
            ? h2bs[((size_t)(kp >> 3) * n + gr) * 8 + (kp & 7)] : 0u;
    }
    for (int idx = tid; idx < 4096; idx += 256) {
        int col = idx & 63, kp = idx >> 6;
        float v0 = W[(size_t)(2 * kp) * 64 + col];
        float v1 = W[(size_t)(2 * kp + 1) * 64 + col];
        B_lds[(((kp >> 2) * 64) + col) * 4 + (kp & 3)] = pack_bf2(v0, v1);
    }
    __syncthreads();

    int arow = w * 16 + (l & 15);
    int kq   = (l >> 4);
    f32x4 acc[4];
    #pragma unroll
    for (int nb = 0; nb < 4; ++nb) acc[nb] = (f32x4){0.f, 0.f, 0.f, 0.f};

    #pragma unroll
    for (int k0 = 0; k0 < 4; ++k0) {
        bf16x8 af = *reinterpret_cast<const bf16x8*>(&A_lds[arow][k0 * 16 + kq * 4]);
        #pragma unroll
        for (int nb = 0; nb < 4; ++nb) {
            const unsigned int* bp = &B_lds[(((k0 * 4 + kq) * 64) + nb * 16 + (l & 15)) * 4];
            bf16x8 bf = *reinterpret_cast<const bf16x8*>(bp);
            acc[nb] = __builtin_amdgcn_mfma_f32_16x16x32_bf16(af, bf, acc[nb], 0, 0, 0);
        }
    }

    #pragma unroll
    for (int r = 0; r < 4; ++r) {
        int gr = row0 + w * 16 + (l >> 4) * 4 + r;
        float di = (gr < M) ? dinv[gr] : 0.f;
        #pragma unroll
        for (int nb = 0; nb < 4; ++nb) {
            float fv = acc[nb][r] * di;
            float pv = __shfl_xor(fv, 1);
            if ((l & 1) == 0 && gr < M) {
                zsb[(size_t)gr * 32 + nb * 8 + ((l & 15) >> 1)] = pack_bf2(fv, pv);
            }
        }
    }
}

// ---------------- Aggregation: XCD channel-sliced gathers ----------------
// R11: each XCD gathers only a 32B channel-slice of the table, so its slice
// (hsb: 3.2MB, zsb: 3.2MB) stays L2-resident. slice = blockIdx&7 relies on
// round-robin block->XCD dispatch (m09/HK T1); if that's wrong it's only slow,
// not incorrect. 8-lane group per node: edge indices loaded coalesced by the
// group (src_sorted[e+w]) and distributed via __shfl.

// Layer 1: h2bs[slice][i][w] = pack(relu(dinv*sum + b1)), word = slice*8+w.
__global__ __launch_bounds__(256) void k_agg1(const unsigned int* __restrict__ hsb,
                                              const float* __restrict__ dinv,
                                              const int* __restrict__ row_ptr,
                                              const int* __restrict__ src_sorted,
                                              const float* __restrict__ b1,
                                              unsigned int* __restrict__ h2bs, int n) {
    int slice = blockIdx.x & 7;
    int i = (blockIdx.x >> 3) * 32 + (threadIdx.x >> 3);
    int w = threadIdx.x & 7;
    if (i >= n) return;
    int word  = slice * 8 + w;
    int gbase = (threadIdx.x & 63) & 56;    // 8-lane group base within wave
    unsigned int v = hsb[(size_t)i * 64 + word];
    float ax = bf_lo(v), ay = bf_hi(v);
    int lo = row_ptr[i], hi = row_ptr[i + 1];
    int e = lo;
    for (; e + 8 <= hi; e += 8) {
        int sv = __builtin_nontemporal_load(&src_sorted[e + w]);
        int s0 = __shfl(sv, gbase + 0);
        int s1 = __shfl(sv, gbase + 1);
        int s2 = __shfl(sv, gbase + 2);
        int s3 = __shfl(sv, gbase + 3);
        int s4 = __shfl(sv, gbase + 4);
        int s5 = __shfl(sv, gbase + 5);
        int s6 = __shfl(sv, gbase + 6);
        int s7 = __shfl(sv, gbase + 7);
        unsigned int w0 = hsb[(size_t)s0 * 64 + word];
        unsigned int w1 = hsb[(size_t)s1 * 64 + word];
        unsigned int w2 = hsb[(size_t)s2 * 64 + word];
        unsigned int w3 = hsb[(size_t)s3 * 64 + word];
        unsigned int w4 = hsb[(size_t)s4 * 64 + word];
        unsigned int w5 = hsb[(size_t)s5 * 64 + word];
        unsigned int w6 = hsb[(size_t)s6 * 64 + word];
        unsigned int w7 = hsb[(size_t)s7 * 64 + word];
        ax += ((bf_lo(w0) + bf_lo(w1)) + (bf_lo(w2) + bf_lo(w3)))
            + ((bf_lo(w4) + bf_lo(w5)) + (bf_lo(w6) + bf_lo(w7)));
        ay += ((bf_hi(w0) + bf_hi(w1)) + (bf_hi(w2) + bf_hi(w3)))
            + ((bf_hi(w4) + bf_hi(w5)) + (bf_hi(w6) + bf_hi(w7)));
    }
    for (; e < hi; ++e) {
        int s = __builtin_nontemporal_load(&src_sorted[e]);
        unsigned int ws = hsb[(size_t)s * 64 + word];
        ax += bf_lo(ws);
        ay += bf_hi(ws);
    }
    float di = dinv[i];
    float2 bb = *reinterpret_cast<const float2*>(&b1[2 * word]);
    float v0 = di * ax + bb.x;
    float v1 = di * ay + bb.y;
    unsigned int pv = pack_bf2(v0 > 0.f ? v0 : 0.f, v1 > 0.f ? v1 : 0.f);
    h2bs[((size_t)slice * n + i) * 8 + w] = pv;   // contiguous per wave
}

// Layer 2: 4 slices x 8 words over zsb's 32 words; 2 XCDs share a slice,
// splitting the node range. out writes are full 64B lines.
__global__ __launch_bounds__(256) void k_agg2(const unsigned int* __restrict__ zsb,
                                              const float* __restrict__ dinv,
                                              const int* __restrict__ row_ptr,
                                              const int* __restrict__ src_sorted,
                                              const float* __restrict__ b2,
                                              float* __restrict__ out, int n) {
    int xcd   = blockIdx.x & 7;
    int slice = xcd >> 1;                    // 0..3
    int nb    = (blockIdx.x >> 3) * 2 + (xcd & 1);
    int i = nb * 32 + (threadIdx.x >> 3);
    int w = threadIdx.x & 7;
    if (i >= n) return;
    int word  = slice * 8 + w;               // 0..31
    int gbase = (threadIdx.x & 63) & 56;
    unsigned int v = zsb[(size_t)i * 32 + word];
    float ax = bf_lo(v), ay = bf_hi(v);
    int lo = row_ptr[i], hi = row_ptr[i + 1];
    int e = lo;
    for (; e + 8 <= hi; e += 8) {
        int sv = __builtin_nontemporal_load(&src_sorted[e + w]);
        int s0 = __shfl(sv, gbase + 0);
        int s1 = __shfl(sv, gbase + 1);
        int s2 = __shfl(sv, gbase + 2);
        int s3 = __shfl(sv, gbase + 3);
        int s4 = __shfl(sv, gbase + 4);
        int s5 = __shfl(sv, gbase + 5);
        int s6 = __shfl(sv, gbase + 6);
        int s7 = __shfl(sv, gbase + 7);
        unsigned int w0 = zsb[(size_t)s0 * 32 + word];
        unsigned int w1 = zsb[(size_t)s1 * 32 + word];
        unsigned int w2 = zsb[(size_t)s2 * 32 + word];
        unsigned int w3 = zsb[(size_t)s3 * 32 + word];
        unsigned int w4 = zsb[(size_t)s4 * 32 + word];
        unsigned int w5 = zsb[(size_t)s5 * 32 + word];
        unsigned int w6 = zsb[(size_t)s6 * 32 + word];
        unsigned int w7 = zsb[(size_t)s7 * 32 + word];
        ax += ((bf_lo(w0) + bf_lo(w1)) + (bf_lo(w2) + bf_lo(w3)))
            + ((bf_lo(w4) + bf_lo(w5)) + (bf_lo(w6) + bf_lo(w7)));
        ay += ((bf_hi(w0) + bf_hi(w1)) + (bf_hi(w2) + bf_hi(w3)))
            + ((bf_hi(w4) + bf_hi(w5)) + (bf_hi(w6) + bf_hi(w7)));
    }
    for (; e < hi; ++e) {
        int s = __builtin_nontemporal_load(&src_sorted[e]);
        unsigned int ws = zsb[(size_t)s * 32 + word];
        ax += bf_lo(ws);
        ay += bf_hi(ws);
    }
    float di = dinv[i];
    float2 bb = *reinterpret_cast<const float2*>(&b2[2 * word]);
    float2 o = {di * ax + bb.x, di * ay + bb.y};
    *reinterpret_cast<float2*>(&out[(size_t)i * 64 + 2 * word]) = o;
}

// ---------------- launch ----------------

static inline size_t alignup(size_t v) { return (v + 255) & ~(size_t)255; }

extern "C" void kernel_launch(void* const* d_in, const int* in_sizes, int n_in,
                              void* d_out, int out_size, void* d_ws, size_t ws_size,
                              hipStream_t stream) {
    const float* x  = (const float*)d_in[0];
    const void*  ei = d_in[1];
    const float* W1 = (const float*)d_in[2];
    const float* b1 = (const float*)d_in[3];
    const float* W2 = (const float*)d_in[4];
    const float* b2 = (const float*)d_in[5];

    const int n = in_sizes[0] / 128;   // 100000
    const int e = in_sizes[1] / 2;     // 3200000

    char* p = (char*)d_ws;
    auto take = [&](size_t bytes) { char* q = p; p += alignup(bytes); return q; };
    size_t pairs_bytes = (size_t)e * 4;            // 12.8 MB
    size_t hsb_bytes   = (size_t)n * 64 * 4;       // 25.6 MB
    size_t regA_bytes  = pairs_bytes > hsb_bytes ? pairs_bytes : hsb_bytes;
    char* regA = (char*)take(regA_bytes);
    unsigned int* pairs = (unsigned int*)regA;     // dead before hsb written
    unsigned int* hsb   = (unsigned int*)regA;

    unsigned int* h2bs       = (unsigned int*)take((size_t)n * 64 * 4);  // [8][n][8]
    int*          is64       = (int*)  take(4);
    float*        dinv       = (float*)take((size_t)n * 4);
    int*          row_ptr    = (int*)  take((size_t)(n + 1) * 4);
    int*          bkt_cnt    = (int*)  take(512 * 4);
    int*          bkt_base   = (int*)  take(513 * 4);
    int*          bkt_cursor = (int*)  take(512 * 4);
    int*          src_sorted = (int*)  take((size_t)e * 4);
    unsigned int* zsb        = (unsigned int*)take((size_t)n * 32 * 4);
    if ((size_t)(p - (char*)d_ws) > ws_size) return;

    const int nb_bkt  = (n + 255) >> 8;
    const int nb_chnk = (e + BKT_CH - 1) / BKT_CH;
    const int nbn32   = (n + 31) / 32;             // 32 nodes per block

    k_detect64<<<1, 256, 0, stream>>>((const unsigned int*)ei, e, is64);
    k_zero512<<<1, 512, 0, stream>>>(bkt_cnt);
    k_hist<<<nb_chnk, 256, 0, stream>>>(ei, e, is64, bkt_cnt);
    k_scan_bkt<<<1, 512, 0, stream>>>(bkt_cnt, bkt_base, bkt_cursor, nb_bkt);
    k_bucket<<<nb_chnk, 256, 0, stream>>>(ei, e, is64, bkt_cursor, pairs);
    k_place_deg<<<nb_bkt, 256, 0, stream>>>(pairs, bkt_base, n, nb_bkt,
                                            row_ptr, dinv, src_sorted);

    k_gemm128<<<(n + 63) / 64, 256, 0, stream>>>(x, W1, dinv, hsb, n);
    k_agg1<<<8 * nbn32, 256, 0, stream>>>(hsb, dinv, row_ptr, src_sorted, b1, h2bs, n);
    k_gemm64<<<(n + 63) / 64, 256, 0, stream>>>(h2bs, W2, dinv, zsb, n, n);
    k_agg2<<<8 * ((nbn32 + 1) / 2), 256, 0, stream>>>(zsb, dinv, row_ptr, src_sorted,
                                                      b2, (float*)d_out, n);
}

// Round 12
// 336.266 us; speedup vs baseline: 2.3183x; 2.3183x over previous
//
#include <hip/hip_runtime.h>
#include <cstdint>
#include <cstddef>

typedef short bf16x8 __attribute__((ext_vector_type(8)));
typedef float f32x4  __attribute__((ext_vector_type(4)));

// ---- bf16 pack/unpack helpers (RNE) ----
static __device__ __forceinline__ unsigned int f2bf_rne(float f) {
    unsigned int u = __float_as_uint(f);
    unsigned int r = 0x7FFFu + ((u >> 16) & 1u);
    return (u + r) >> 16;
}
static __device__ __forceinline__ unsigned int pack_bf2(float lo, float hi) {
    return f2bf_rne(lo) | (f2bf_rne(hi) << 16);
}
static __device__ __forceinline__ float bf_lo(unsigned int w) {
    return __uint_as_float(w << 16);
}
static __device__ __forceinline__ float bf_hi(unsigned int w) {
    return __uint_as_float(w & 0xFFFF0000u);
}

#define BKT_CH 8192    // edges per chunk-block (fits LDS staging: 2x32KB)

// ---------------- CSR build (R6-R8: zero per-edge global atomics) ----------------
// R5+R11 lesson (twice-confirmed): blockIdx&7 -> XCD mapping does NOT give
// per-XCD L2 residency on this dispatch path. No XCD-affinity tricks.

__global__ void k_detect64(const unsigned int* ei, int e, int* is64) {
    __shared__ int nonzero;
    if (threadIdx.x == 0) nonzero = 0;
    __syncthreads();
    for (int i = threadIdx.x; i < 4096; i += blockDim.x) {
        size_t k = (size_t)((unsigned long long)i * (unsigned long long)e / 4096ull);
        if (ei[2 * k + 1] != 0u) nonzero = 1;   // racy OR, fine
    }
    __syncthreads();
    if (threadIdx.x == 0) *is64 = nonzero ? 0 : 1;
}

__global__ void k_zero512(int* p) { p[threadIdx.x] = 0; }

__global__ __launch_bounds__(256) void k_hist(const void* ei_raw, int e, const int* is64,
                                              int* __restrict__ bkt_cnt) {
    __shared__ int lcnt[512];
    int t = threadIdx.x;
    for (int j = t; j < 512; j += 256) lcnt[j] = 0;
    __syncthreads();
    int lo = blockIdx.x * BKT_CH;
    int hi = lo + BKT_CH; if (hi > e) hi = e;
    if (*is64) {
        const long long* p = (const long long*)ei_raw;
        for (int i = lo + t; i < hi; i += 256)
            atomicAdd(&lcnt[((int)p[(size_t)e + i]) >> 8], 1);
    } else {
        const int* p = (const int*)ei_raw;
        for (int i = lo + t; i < hi; i += 256)
            atomicAdd(&lcnt[p[(size_t)e + i] >> 8], 1);
    }
    __syncthreads();
    for (int j = t; j < 512; j += 256)
        if (lcnt[j]) atomicAdd(&bkt_cnt[j], lcnt[j]);
}

__global__ __launch_bounds__(512) void k_scan_bkt(const int* __restrict__ bkt_cnt,
                                                  int* __restrict__ bkt_base,
                                                  int* __restrict__ bkt_cursor, int nb) {
    __shared__ int s[512];
    int t = threadIdx.x;
    int v = (t < nb) ? bkt_cnt[t] : 0;
    s[t] = v;
    __syncthreads();
    #pragma unroll
    for (int d = 1; d < 512; d <<= 1) {
        int tmp = (t >= d) ? s[t - d] : 0;
        __syncthreads();
        s[t] += tmp;
        __syncthreads();
    }
    if (t < nb) {
        int b = s[t] - v;
        bkt_base[t]   = b;
        bkt_cursor[t] = b;
    }
    if (t == 511) bkt_base[nb] = s[511];
}

__global__ __launch_bounds__(256) void k_bucket(const void* ei_raw, int e, const int* is64,
                                                int* __restrict__ bkt_cursor,
                                                unsigned int* __restrict__ pout) {
    __shared__ int ldst[BKT_CH];
    __shared__ int lsrc[BKT_CH];
    __shared__ int lcnt[512];
    __shared__ int lbase[512];
    int t = threadIdx.x;
    int lo = blockIdx.x * BKT_CH;
    int hi = lo + BKT_CH; if (hi > e) hi = e;
    int m = hi - lo;
    for (int j = t; j < 512; j += 256) lcnt[j] = 0;
    __syncthreads();
    bool w64 = (*is64 != 0);
    const long long* p64 = (const long long*)ei_raw;
    const int*       p32 = (const int*)ei_raw;
    for (int idx = t; idx < m; idx += 256) {
        size_t i = (size_t)lo + idx;
        int s, d;
        if (w64) { s = (int)p64[i]; d = (int)p64[(size_t)e + i]; }
        else     { s = p32[i];      d = p32[(size_t)e + i]; }
        ldst[idx] = d;
        lsrc[idx] = s;
        atomicAdd(&lcnt[d >> 8], 1);
    }
    __syncthreads();
    for (int j = t; j < 512; j += 256) {
        int c = lcnt[j];
        lbase[j] = c ? atomicAdd(&bkt_cursor[j], c) : 0;
        lcnt[j] = 0;
    }
    __syncthreads();
    for (int idx = t; idx < m; idx += 256) {
        int d = ldst[idx], s = lsrc[idx];
        int b = d >> 8;
        int pos = lbase[b] + atomicAdd(&lcnt[b], 1);
        pout[pos] = ((unsigned int)(d & 255) << 24) | (unsigned int)s;
    }
}

__global__ __launch_bounds__(256) void k_place_deg(const unsigned int* __restrict__ pairs,
                                                   const int* __restrict__ bkt_base,
                                                   int n, int nb,
                                                   int* __restrict__ row_ptr,
                                                   float* __restrict__ dinv,
                                                   int* __restrict__ src_sorted) {
    __shared__ int lcnt[256];
    __shared__ int ls[256];
    __shared__ int lcur[256];
    int b = blockIdx.x;
    int t = threadIdx.x;
    int base = bkt_base[b], end = bkt_base[b + 1];
    lcnt[t] = 0;
    __syncthreads();
    for (int i = base + t; i < end; i += 256)
        atomicAdd(&lcnt[__builtin_nontemporal_load(&pairs[i]) >> 24], 1);
    __syncthreads();
    int v = lcnt[t];
    ls[t] = v;
    __syncthreads();
    #pragma unroll
    for (int d = 1; d < 256; d <<= 1) {
        int tmp = (t >= d) ? ls[t - d] : 0;
        __syncthreads();
        ls[t] += tmp;
        __syncthreads();
    }
    int nodebase = base + ls[t] - v;
    int node = (b << 8) + t;
    if (node < n) {
        row_ptr[node] = nodebase;
        dinv[node] = rsqrtf((float)(v + 1));
    }
    lcur[t] = nodebase;
    __syncthreads();
    for (int i = base + t; i < end; i += 256) {
        unsigned int pr = __builtin_nontemporal_load(&pairs[i]);
        int pos = atomicAdd(&lcur[pr >> 24], 1);
        src_sorted[pos] = (int)(pr & 0x00FFFFFFu);
    }
    if (t == 0 && b == nb - 1) row_ptr[n] = end;
}

// ---------------- Layer-1 GEMM: MFMA bf16 16x16x32 (R10) ----------------
__global__ __launch_bounds__(256) void k_gemm128(const float* __restrict__ A,
                                                 const float* __restrict__ W,
                                                 const float* __restrict__ dinv,
                                                 unsigned int* __restrict__ hsb, int M) {
    __shared__ unsigned int A_lds[64][68];
    __shared__ unsigned int B_lds[16 * 128 * 4];
    int tid = threadIdx.x;
    int w   = tid >> 6;
    int l   = tid & 63;
    int row0 = blockIdx.x * 64;

    for (int idx = tid; idx < 4096; idx += 256) {
        int r = idx >> 6, kp = idx & 63;
        unsigned int pv = 0u;
        int gr = row0 + r;
        if (gr < M) {
            float2 f = *reinterpret_cast<const float2*>(&A[(size_t)gr * 128 + 2 * kp]);
            pv = pack_bf2(f.x, f.y);
        }
        A_lds[r][kp] = pv;
    }
    for (int idx = tid; idx < 8192; idx += 256) {
        int col = idx & 127, kp = idx >> 7;
        float v0 = W[(size_t)(2 * kp) * 128 + col];
        float v1 = W[(size_t)(2 * kp + 1) * 128 + col];
        B_lds[(((kp >> 2) * 128) + col) * 4 + (kp & 3)] = pack_bf2(v0, v1);
    }
    __syncthreads();

    int arow = w * 16 + (l & 15);
    int kq   = (l >> 4);
    f32x4 acc[8];
    #pragma unroll
    for (int nb = 0; nb < 8; ++nb) acc[nb] = (f32x4){0.f, 0.f, 0.f, 0.f};

    #pragma unroll
    for (int k0 = 0; k0 < 4; ++k0) {
        bf16x8 af = *reinterpret_cast<const bf16x8*>(&A_lds[arow][k0 * 16 + kq * 4]);
        #pragma unroll
        for (int nb = 0; nb < 8; ++nb) {
            const unsigned int* bp = &B_lds[(((k0 * 4 + kq) * 128) + nb * 16 + (l & 15)) * 4];
            bf16x8 bf = *reinterpret_cast<const bf16x8*>(bp);
            acc[nb] = __builtin_amdgcn_mfma_f32_16x16x32_bf16(af, bf, acc[nb], 0, 0, 0);
        }
    }

    #pragma unroll
    for (int r = 0; r < 4; ++r) {
        int gr = row0 + w * 16 + (l >> 4) * 4 + r;
        float di = (gr < M) ? dinv[gr] : 0.f;
        #pragma unroll
        for (int nb = 0; nb < 8; ++nb) {
            float fv = acc[nb][r] * di;
            float pv = __shfl_xor(fv, 1);
            if ((l & 1) == 0 && gr < M) {
                hsb[(size_t)gr * 64 + nb * 8 + ((l & 15) >> 1)] = pack_bf2(fv, pv);
            }
        }
    }
}

// ---------------- Layer-2 GEMM: MFMA bf16 16x16x32 (R10) ----------------
__global__ __launch_bounds__(256) void k_gemm64(const unsigned int* __restrict__ Ab,
                                                const float* __restrict__ W,
                                                const float* __restrict__ dinv,
                                                unsigned int* __restrict__ zsb, int M) {
    __shared__ unsigned int A_lds[64][68];
    __shared__ unsigned int B_lds[16 * 64 * 4];
    int tid = threadIdx.x;
    int w   = tid >> 6;
    int l   = tid & 63;
    int row0 = blockIdx.x * 64;

    for (int idx = tid; idx < 4096; idx += 256) {
        int r = idx >> 6, kp = idx & 63;
        int gr = row0 + r;
        A_lds[r][kp] = (gr < M) ? Ab[(size_t)gr * 64 + kp] : 0u;
    }
    for (int idx = tid; idx < 4096; idx += 256) {
        int col = idx & 63, kp = idx >> 6;
        float v0 = W[(size_t)(2 * kp) * 64 + col];
        float v1 = W[(size_t)(2 * kp + 1) * 64 + col];
        B_lds[(((kp >> 2) * 64) + col) * 4 + (kp & 3)] = pack_bf2(v0, v1);
    }
    __syncthreads();

    int arow = w * 16 + (l & 15);
    int kq   = (l >> 4);
    f32x4 acc[4];
    #pragma unroll
    for (int nb = 0; nb < 4; ++nb) acc[nb] = (f32x4){0.f, 0.f, 0.f, 0.f};

    #pragma unroll
    for (int k0 = 0; k0 < 4; ++k0) {
        bf16x8 af = *reinterpret_cast<const bf16x8*>(&A_lds[arow][k0 * 16 + kq * 4]);
        #pragma unroll
        for (int nb = 0; nb < 4; ++nb) {
            const unsigned int* bp = &B_lds[(((k0 * 4 + kq) * 64) + nb * 16 + (l & 15)) * 4];
            bf16x8 bf = *reinterpret_cast<const bf16x8*>(bp);
            acc[nb] = __builtin_amdgcn_mfma_f32_16x16x32_bf16(af, bf, acc[nb], 0, 0, 0);
        }
    }

    #pragma unroll
    for (int r = 0; r < 4; ++r) {
        int gr = row0 + w * 16 + (l >> 4) * 4 + r;
        float di = (gr < M) ? dinv[gr] : 0.f;
        #pragma unroll
        for (int nb = 0; nb < 4; ++nb) {
            float fv = acc[nb][r] * di;
            float pv = __shfl_xor(fv, 1);
            if ((l & 1) == 0 && gr < M) {
                zsb[(size_t)gr * 32 + nb * 8 + ((l & 15) >> 1)] = pack_bf2(fv, pv);
            }
        }
    }
}

// ---------------- Aggregation (R10 pattern; R12: bigger blocks, fewer dispatches) ----------------

// h2b[i][c] = pack_bf16(relu(dinv[i]*sum + b1[2c..2c+1])); 4 nodes per
// 256-thread block, one wave per node (identical per-wave memory pattern to
// R10's 64-thread version; 100K -> 25K blocks).
__global__ __launch_bounds__(256) void k_agg1(const unsigned int* __restrict__ hsb,
                                              const float* __restrict__ dinv,
                                              const int* __restrict__ row_ptr,
                                              const int* __restrict__ src_sorted,
                                              const float* __restrict__ b1,
                                              unsigned int* __restrict__ h2b, int n) {
    int i = blockIdx.x * 4 + (threadIdx.x >> 6);
    int c = threadIdx.x & 63;
    if (i >= n) return;
    unsigned int w = hsb[(size_t)i * 64 + c];
    float ax = bf_lo(w), ay = bf_hi(w);
    int lo = row_ptr[i], hi = row_ptr[i + 1];
    int e = lo;
    for (; e + 8 <= hi; e += 8) {
        int s0 = __builtin_nontemporal_load(&src_sorted[e + 0]);
        int s1 = __builtin_nontemporal_load(&src_sorted[e + 1]);
        int s2 = __builtin_nontemporal_load(&src_sorted[e + 2]);
        int s3 = __builtin_nontemporal_load(&src_sorted[e + 3]);
        int s4 = __builtin_nontemporal_load(&src_sorted[e + 4]);
        int s5 = __builtin_nontemporal_load(&src_sorted[e + 5]);
        int s6 = __builtin_nontemporal_load(&src_sorted[e + 6]);
        int s7 = __builtin_nontemporal_load(&src_sorted[e + 7]);
        unsigned int w0 = hsb[(size_t)s0 * 64 + c];
        unsigned int w1 = hsb[(size_t)s1 * 64 + c];
        unsigned int w2 = hsb[(size_t)s2 * 64 + c];
        unsigned int w3 = hsb[(size_t)s3 * 64 + c];
        unsigned int w4 = hsb[(size_t)s4 * 64 + c];
        unsigned int w5 = hsb[(size_t)s5 * 64 + c];
        unsigned int w6 = hsb[(size_t)s6 * 64 + c];
        unsigned int w7 = hsb[(size_t)s7 * 64 + c];
        ax += ((bf_lo(w0) + bf_lo(w1)) + (bf_lo(w2) + bf_lo(w3)))
            + ((bf_lo(w4) + bf_lo(w5)) + (bf_lo(w6) + bf_lo(w7)));
        ay += ((bf_hi(w0) + bf_hi(w1)) + (bf_hi(w2) + bf_hi(w3)))
            + ((bf_hi(w4) + bf_hi(w5)) + (bf_hi(w6) + bf_hi(w7)));
    }
    if (e + 4 <= hi) {
        int s0 = __builtin_nontemporal_load(&src_sorted[e + 0]);
        int s1 = __builtin_nontemporal_load(&src_sorted[e + 1]);
        int s2 = __builtin_nontemporal_load(&src_sorted[e + 2]);
        int s3 = __builtin_nontemporal_load(&src_sorted[e + 3]);
        unsigned int w0 = hsb[(size_t)s0 * 64 + c];
        unsigned int w1 = hsb[(size_t)s1 * 64 + c];
        unsigned int w2 = hsb[(size_t)s2 * 64 + c];
        unsigned int w3 = hsb[(size_t)s3 * 64 + c];
        ax += (bf_lo(w0) + bf_lo(w1)) + (bf_lo(w2) + bf_lo(w3));
        ay += (bf_hi(w0) + bf_hi(w1)) + (bf_hi(w2) + bf_hi(w3));
        e += 4;
    }
    for (; e < hi; ++e) {
        int s = __builtin_nontemporal_load(&src_sorted[e]);
        unsigned int ws = hsb[(size_t)s * 64 + c];
        ax += bf_lo(ws);
        ay += bf_hi(ws);
    }
    float di = dinv[i];
    float2 bb = *reinterpret_cast<const float2*>(&b1[2 * c]);
    float v0 = di * ax + bb.x;
    float v1 = di * ay + bb.y;
    unsigned int pv = pack_bf2(v0 > 0.f ? v0 : 0.f, v1 > 0.f ? v1 : 0.f);
    __builtin_nontemporal_store(pv, &h2b[(size_t)i * 64 + c]);
}

// out[i][2c..2c+1] = dinv[i]*(zsb_sum) + b2; 8 nodes per 256-thread block
// (32-lane group per node; 50K -> 12.5K blocks).
__global__ __launch_bounds__(256) void k_agg2(const unsigned int* __restrict__ zsb,
                                              const float* __restrict__ dinv,
                                              const int* __restrict__ row_ptr,
                                              const int* __restrict__ src_sorted,
                                              const float* __restrict__ b2,
                                              float* __restrict__ out, int n) {
    int i = blockIdx.x * 8 + (threadIdx.x >> 5);
    int c = threadIdx.x & 31;
    if (i >= n) return;
    unsigned int w = zsb[(size_t)i * 32 + c];
    float ax = bf_lo(w), ay = bf_hi(w);
    int lo = row_ptr[i], hi = row_ptr[i + 1];
    int e = lo;
    for (; e + 8 <= hi; e += 8) {
        int s0 = __builtin_nontemporal_load(&src_sorted[e + 0]);
        int s1 = __builtin_nontemporal_load(&src_sorted[e + 1]);
        int s2 = __builtin_nontemporal_load(&src_sorted[e + 2]);
        int s3 = __builtin_nontemporal_load(&src_sorted[e + 3]);
        int s4 = __builtin_nontemporal_load(&src_sorted[e + 4]);
        int s5 = __builtin_nontemporal_load(&src_sorted[e + 5]);
        int s6 = __builtin_nontemporal_load(&src_sorted[e + 6]);
        int s7 = __builtin_nontemporal_load(&src_sorted[e + 7]);
        unsigned int w0 = zsb[(size_t)s0 * 32 + c];
        unsigned int w1 = zsb[(size_t)s1 * 32 + c];
        unsigned int w2 = zsb[(size_t)s2 * 32 + c];
        unsigned int w3 = zsb[(size_t)s3 * 32 + c];
        unsigned int w4 = zsb[(size_t)s4 * 32 + c];
        unsigned int w5 = zsb[(size_t)s5 * 32 + c];
        unsigned int w6 = zsb[(size_t)s6 * 32 + c];
        unsigned int w7 = zsb[(size_t)s7 * 32 + c];
        ax += ((bf_lo(w0) + bf_lo(w1)) + (bf_lo(w2) + bf_lo(w3)))
            + ((bf_lo(w4) + bf_lo(w5)) + (bf_lo(w6) + bf_lo(w7)));
        ay += ((bf_hi(w0) + bf_hi(w1)) + (bf_hi(w2) + bf_hi(w3)))
            + ((bf_hi(w4) + bf_hi(w5)) + (bf_hi(w6) + bf_hi(w7)));
    }
    if (e + 4 <= hi) {
        int s0 = __builtin_nontemporal_load(&src_sorted[e + 0]);
        int s1 = __builtin_nontemporal_load(&src_sorted[e + 1]);
        int s2 = __builtin_nontemporal_load(&src_sorted[e + 2]);
        int s3 = __builtin_nontemporal_load(&src_sorted[e + 3]);
        unsigned int w0 = zsb[(size_t)s0 * 32 + c];
        unsigned int w1 = zsb[(size_t)s1 * 32 + c];
        unsigned int w2 = zsb[(size_t)s2 * 32 + c];
        unsigned int w3 = zsb[(size_t)s3 * 32 + c];
        ax += (bf_lo(w0) + bf_lo(w1)) + (bf_lo(w2) + bf_lo(w3));
        ay += (bf_hi(w0) + bf_hi(w1)) + (bf_hi(w2) + bf_hi(w3));
        e += 4;
    }
    for (; e < hi; ++e) {
        int s = __builtin_nontemporal_load(&src_sorted[e]);
        unsigned int ws = zsb[(size_t)s * 32 + c];
        ax += bf_lo(ws);
        ay += bf_hi(ws);
    }
    float di = dinv[i];
    float2 bb = *reinterpret_cast<const float2*>(&b2[2 * c]);
    float2 o = {di * ax + bb.x, di * ay + bb.y};
    *reinterpret_cast<float2*>(&out[(size_t)i * 64 + 2 * c]) = o;
}

// ---------------- launch ----------------

static inline size_t alignup(size_t v) { return (v + 255) & ~(size_t)255; }

extern "C" void kernel_launch(void* const* d_in, const int* in_sizes, int n_in,
                              void* d_out, int out_size, void* d_ws, size_t ws_size,
                              hipStream_t stream) {
    const float* x  = (const float*)d_in[0];
    const void*  ei = d_in[1];
    const float* W1 = (const float*)d_in[2];
    const float* b1 = (const float*)d_in[3];
    const float* W2 = (const float*)d_in[4];
    const float* b2 = (const float*)d_in[5];

    const int n = in_sizes[0] / 128;   // 100000
    const int e = in_sizes[1] / 2;     // 3200000

    char* p = (char*)d_ws;
    auto take = [&](size_t bytes) { char* q = p; p += alignup(bytes); return q; };
    size_t pairs_bytes = (size_t)e * 4;            // 12.8 MB
    size_t hsb_bytes   = (size_t)n * 64 * 4;       // 25.6 MB
    size_t regA_bytes  = pairs_bytes > hsb_bytes ? pairs_bytes : hsb_bytes;
    char* regA = (char*)take(regA_bytes);
    unsigned int* pairs = (unsigned int*)regA;     // dead before hsb written
    unsigned int* hsb   = (unsigned int*)regA;

    unsigned int* h2b        = (unsigned int*)take((size_t)n * 64 * 4);
    int*          is64       = (int*)  take(4);
    float*        dinv       = (float*)take((size_t)n * 4);
    int*          row_ptr    = (int*)  take((size_t)(n + 1) * 4);
    int*          bkt_cnt    = (int*)  take(512 * 4);
    int*          bkt_base   = (int*)  take(513 * 4);
    int*          bkt_cursor = (int*)  take(512 * 4);
    int*          src_sorted = (int*)  take((size_t)e * 4);
    unsigned int* zsb        = (unsigned int*)take((size_t)n * 32 * 4);
    if ((size_t)(p - (char*)d_ws) > ws_size) return;

    const int nb_bkt  = (n + 255) >> 8;
    const int nb_chnk = (e + BKT_CH - 1) / BKT_CH;

    k_detect64<<<1, 256, 0, stream>>>((const unsigned int*)ei, e, is64);
    k_zero512<<<1, 512, 0, stream>>>(bkt_cnt);
    k_hist<<<nb_chnk, 256, 0, stream>>>(ei, e, is64, bkt_cnt);
    k_scan_bkt<<<1, 512, 0, stream>>>(bkt_cnt, bkt_base, bkt_cursor, nb_bkt);
    k_bucket<<<nb_chnk, 256, 0, stream>>>(ei, e, is64, bkt_cursor, pairs);
    k_place_deg<<<nb_bkt, 256, 0, stream>>>(pairs, bkt_base, n, nb_bkt,
                                            row_ptr, dinv, src_sorted);

    k_gemm128<<<(n + 63) / 64, 256, 0, stream>>>(x, W1, dinv, hsb, n);
    k_agg1<<<(n + 3) / 4, 256, 0, stream>>>(hsb, dinv, row_ptr, src_sorted, b1, h2b, n);
    k_gemm64<<<(n + 63) / 64, 256, 0, stream>>>(h2b, W2, dinv, zsb, n);
    k_agg2<<<(n + 7) / 8, 256, 0, stream>>>(zsb, dinv, row_ptr, src_sorted, b2, (float*)d_out, n);
}

// Round 13
// 306.266 us; speedup vs baseline: 2.5454x; 1.0980x over previous
//
#include <hip/hip_runtime.h>
#include <cstdint>
#include <cstddef>

typedef short bf16x8 __attribute__((ext_vector_type(8)));
typedef float f32x4  __attribute__((ext_vector_type(4)));

// ---- bf16 pack/unpack helpers (RNE) ----
static __device__ __forceinline__ unsigned int f2bf_rne(float f) {
    unsigned int u = __float_as_uint(f);
    unsigned int r = 0x7FFFu + ((u >> 16) & 1u);
    return (u + r) >> 16;
}
static __device__ __forceinline__ unsigned int pack_bf2(float lo, float hi) {
    return f2bf_rne(lo) | (f2bf_rne(hi) << 16);
}
static __device__ __forceinline__ float bf_lo(unsigned int w) {
    return __uint_as_float(w << 16);
}
static __device__ __forceinline__ float bf_hi(unsigned int w) {
    return __uint_as_float(w & 0xFFFF0000u);
}

#define BKT_CH 8192    // edges per chunk-block (LDS staging 2x32KB)
#define BKT_CAP 16384  // slot capacity per bucket (mean fill 8184, >80 sigma)

// ---------------- CSR build ----------------
// R6: zero per-edge global atomics. R5+R11 (twice-confirmed): blockIdx&7->XCD
// gives no L2 residency -- no XCD-affinity tricks. R13: k_hist dropped; buckets
// get fixed-capacity slots, bases from post-hoc cursor deltas.

__global__ void k_detect64(const unsigned int* ei, int e, int* is64) {
    __shared__ int nonzero;
    if (threadIdx.x == 0) nonzero = 0;
    __syncthreads();
    for (int i = threadIdx.x; i < 4096; i += blockDim.x) {
        size_t k = (size_t)((unsigned long long)i * (unsigned long long)e / 4096ull);
        if (ei[2 * k + 1] != 0u) nonzero = 1;   // racy OR, fine
    }
    __syncthreads();
    if (threadIdx.x == 0) *is64 = nonzero ? 0 : 1;
}

__global__ void k_init_cursor(int* bkt_cursor) {
    bkt_cursor[threadIdx.x] = threadIdx.x * BKT_CAP;
}

// Single-pass bucketing into fixed-capacity slots. One block per 8K-edge
// chunk; edges staged in LDS (single global edge read); per-(block,bucket)
// reservation via one global atomic (~153K total).
__global__ __launch_bounds__(256) void k_bucket_direct(const void* ei_raw, int e,
                                                       const int* is64,
                                                       int* __restrict__ bkt_cursor,
                                                       unsigned int* __restrict__ pout) {
    __shared__ int ldst[BKT_CH];
    __shared__ int lsrc[BKT_CH];
    __shared__ int lcnt[512];
    __shared__ int lbase[512];
    int t = threadIdx.x;
    int lo = blockIdx.x * BKT_CH;
    int hi = lo + BKT_CH; if (hi > e) hi = e;
    int m = hi - lo;
    for (int j = t; j < 512; j += 256) lcnt[j] = 0;
    __syncthreads();
    bool w64 = (*is64 != 0);
    const long long* p64 = (const long long*)ei_raw;
    const int*       p32 = (const int*)ei_raw;
    for (int idx = t; idx < m; idx += 256) {
        size_t i = (size_t)lo + idx;
        int s, d;
        if (w64) { s = (int)p64[i]; d = (int)p64[(size_t)e + i]; }
        else     { s = p32[i];      d = p32[(size_t)e + i]; }
        ldst[idx] = d;
        lsrc[idx] = s;
        atomicAdd(&lcnt[d >> 8], 1);
    }
    __syncthreads();
    for (int j = t; j < 512; j += 256) {
        int c = lcnt[j];
        lbase[j] = c ? atomicAdd(&bkt_cursor[j], c) : 0;
        lcnt[j] = 0;                        // running offset for scatter
    }
    __syncthreads();
    for (int idx = 0; idx < m; idx += 256) {
        int k = idx + t;
        if (k < m) {
            int d = ldst[k], s = lsrc[k];
            int b = d >> 8;
            int pos = lbase[b] + atomicAdd(&lcnt[b], 1);
            pout[pos] = ((unsigned int)(d & 255) << 24) | (unsigned int)s;
        }
    }
}

// Exclusive scan of bucket fills (cursor[b] - b*CAP) -> bkt_base[0..nb].
__global__ __launch_bounds__(512) void k_scan_bkt(const int* __restrict__ bkt_cursor,
                                                  int* __restrict__ bkt_base, int nb) {
    __shared__ int s[512];
    int t = threadIdx.x;
    int v = (t < nb) ? (bkt_cursor[t] - t * BKT_CAP) : 0;
    s[t] = v;
    __syncthreads();
    #pragma unroll
    for (int d = 1; d < 512; d <<= 1) {
        int tmp = (t >= d) ? s[t - d] : 0;
        __syncthreads();
        s[t] += tmp;
        __syncthreads();
    }
    if (t < nb) bkt_base[t] = s[t] - v;
    if (t == 511) bkt_base[nb] = s[511];
}

// One block per bucket: per-node LDS counts -> row_ptr + dinv; LDS cursors
// scatter slot pairs into the compact src_sorted. Single-block window ->
// full-line writebacks.
__global__ __launch_bounds__(256) void k_place_deg(const unsigned int* __restrict__ pairs,
                                                   const int* __restrict__ bkt_base,
                                                   const int* __restrict__ bkt_cursor,
                                                   int n, int nb,
                                                   int* __restrict__ row_ptr,
                                                   float* __restrict__ dinv,
                                                   int* __restrict__ src_sorted) {
    __shared__ int lcnt[256];
    __shared__ int ls[256];
    __shared__ int lcur[256];
    int b = blockIdx.x;
    int t = threadIdx.x;
    int slot0 = b * BKT_CAP;
    int slot1 = bkt_cursor[b];             // slot0 + fill
    int obase = bkt_base[b];
    lcnt[t] = 0;
    __syncthreads();
    for (int i = slot0 + t; i < slot1; i += 256)
        atomicAdd(&lcnt[__builtin_nontemporal_load(&pairs[i]) >> 24], 1);
    __syncthreads();
    int v = lcnt[t];
    ls[t] = v;
    __syncthreads();
    #pragma unroll
    for (int d = 1; d < 256; d <<= 1) {
        int tmp = (t >= d) ? ls[t - d] : 0;
        __syncthreads();
        ls[t] += tmp;
        __syncthreads();
    }
    int nodebase = obase + ls[t] - v;      // exclusive within bucket
    int node = (b << 8) + t;
    if (node < n) {
        row_ptr[node] = nodebase;
        dinv[node] = rsqrtf((float)(v + 1));
    }
    lcur[t] = nodebase;
    __syncthreads();
    for (int i = slot0 + t; i < slot1; i += 256) {
        unsigned int pr = __builtin_nontemporal_load(&pairs[i]);
        int pos = atomicAdd(&lcur[pr >> 24], 1);
        src_sorted[pos] = (int)(pr & 0x00FFFFFFu);
    }
    if (t == 0 && b == nb - 1) row_ptr[n] = obase + (slot1 - slot0);
}

// ---------------- Layer-1 GEMM: MFMA bf16 16x16x32 (R10) ----------------
__global__ __launch_bounds__(256) void k_gemm128(const float* __restrict__ A,
                                                 const float* __restrict__ W,
                                                 const float* __restrict__ dinv,
                                                 unsigned int* __restrict__ hsb, int M) {
    __shared__ unsigned int A_lds[64][68];
    __shared__ unsigned int B_lds[16 * 128 * 4];
    int tid = threadIdx.x;
    int w   = tid >> 6;
    int l   = tid & 63;
    int row0 = blockIdx.x * 64;

    for (int idx = tid; idx < 4096; idx += 256) {
        int r = idx >> 6, kp = idx & 63;
        unsigned int pv = 0u;
        int gr = row0 + r;
        if (gr < M) {
            float2 f = *reinterpret_cast<const float2*>(&A[(size_t)gr * 128 + 2 * kp]);
            pv = pack_bf2(f.x, f.y);
        }
        A_lds[r][kp] = pv;
    }
    for (int idx = tid; idx < 8192; idx += 256) {
        int col = idx & 127, kp = idx >> 7;
        float v0 = W[(size_t)(2 * kp) * 128 + col];
        float v1 = W[(size_t)(2 * kp + 1) * 128 + col];
        B_lds[(((kp >> 2) * 128) + col) * 4 + (kp & 3)] = pack_bf2(v0, v1);
    }
    __syncthreads();

    int arow = w * 16 + (l & 15);
    int kq   = (l >> 4);
    f32x4 acc[8];
    #pragma unroll
    for (int nb = 0; nb < 8; ++nb) acc[nb] = (f32x4){0.f, 0.f, 0.f, 0.f};

    #pragma unroll
    for (int k0 = 0; k0 < 4; ++k0) {
        bf16x8 af = *reinterpret_cast<const bf16x8*>(&A_lds[arow][k0 * 16 + kq * 4]);
        #pragma unroll
        for (int nb = 0; nb < 8; ++nb) {
            const unsigned int* bp = &B_lds[(((k0 * 4 + kq) * 128) + nb * 16 + (l & 15)) * 4];
            bf16x8 bf = *reinterpret_cast<const bf16x8*>(bp);
            acc[nb] = __builtin_amdgcn_mfma_f32_16x16x32_bf16(af, bf, acc[nb], 0, 0, 0);
        }
    }

    #pragma unroll
    for (int r = 0; r < 4; ++r) {
        int gr = row0 + w * 16 + (l >> 4) * 4 + r;
        float di = (gr < M) ? dinv[gr] : 0.f;
        #pragma unroll
        for (int nb = 0; nb < 8; ++nb) {
            float fv = acc[nb][r] * di;
            float pv = __shfl_xor(fv, 1);
            if ((l & 1) == 0 && gr < M) {
                hsb[(size_t)gr * 64 + nb * 8 + ((l & 15) >> 1)] = pack_bf2(fv, pv);
            }
        }
    }
}

// ---------------- Layer-2 GEMM: MFMA bf16 16x16x32 (R10) ----------------
__global__ __launch_bounds__(256) void k_gemm64(const unsigned int* __restrict__ Ab,
                                                const float* __restrict__ W,
                                                const float* __restrict__ dinv,
                                                unsigned int* __restrict__ zsb, int M) {
    __shared__ unsigned int A_lds[64][68];
    __shared__ unsigned int B_lds[16 * 64 * 4];
    int tid = threadIdx.x;
    int w   = tid >> 6;
    int l   = tid & 63;
    int row0 = blockIdx.x * 64;

    for (int idx = tid; idx < 4096; idx += 256) {
        int r = idx >> 6, kp = idx & 63;
        int gr = row0 + r;
        A_lds[r][kp] = (gr < M) ? Ab[(size_t)gr * 64 + kp] : 0u;
    }
    for (int idx = tid; idx < 4096; idx += 256) {
        int col = idx & 63, kp = idx >> 6;
        float v0 = W[(size_t)(2 * kp) * 64 + col];
        float v1 = W[(size_t)(2 * kp + 1) * 64 + col];
        B_lds[(((kp >> 2) * 64) + col) * 4 + (kp & 3)] = pack_bf2(v0, v1);
    }
    __syncthreads();

    int arow = w * 16 + (l & 15);
    int kq   = (l >> 4);
    f32x4 acc[4];
    #pragma unroll
    for (int nb = 0; nb < 4; ++nb) acc[nb] = (f32x4){0.f, 0.f, 0.f, 0.f};

    #pragma unroll
    for (int k0 = 0; k0 < 4; ++k0) {
        bf16x8 af = *reinterpret_cast<const bf16x8*>(&A_lds[arow][k0 * 16 + kq * 4]);
        #pragma unroll
        for (int nb = 0; nb < 4; ++nb) {
            const unsigned int* bp = &B_lds[(((k0 * 4 + kq) * 64) + nb * 16 + (l & 15)) * 4];
            bf16x8 bf = *reinterpret_cast<const bf16x8*>(bp);
            acc[nb] = __builtin_amdgcn_mfma_f32_16x16x32_bf16(af, bf, acc[nb], 0, 0, 0);
        }
    }

    #pragma unroll
    for (int r = 0; r < 4; ++r) {
        int gr = row0 + w * 16 + (l >> 4) * 4 + r;
        float di = (gr < M) ? dinv[gr] : 0.f;
        #pragma unroll
        for (int nb = 0; nb < 4; ++nb) {
            float fv = acc[nb][r] * di;
            float pv = __shfl_xor(fv, 1);
            if ((l & 1) == 0 && gr < M) {
                zsb[(size_t)gr * 32 + nb * 8 + ((l & 15) >> 1)] = pack_bf2(fv, pv);
            }
        }
    }
}

// ---------------- Aggregation (exact R10: 64-thread blocks, best measured) ----------------
// R12 lesson: packing multiple nodes per block hurts (wave imbalance, -6% occ).

// h2b[i][c] = pack_bf16(relu(dinv[i]*sum + b1[2c..2c+1])), one wave per node.
__global__ __launch_bounds__(64) void k_agg1(const unsigned int* __restrict__ hsb,
                                             const float* __restrict__ dinv,
                                             const int* __restrict__ row_ptr,
                                             const int* __restrict__ src_sorted,
                                             const float* __restrict__ b1,
                                             unsigned int* __restrict__ h2b) {
    int i = blockIdx.x;
    int c = threadIdx.x;
    unsigned int w = hsb[(size_t)i * 64 + c];
    float ax = bf_lo(w), ay = bf_hi(w);
    int lo = row_ptr[i], hi = row_ptr[i + 1];
    int e = lo;
    for (; e + 8 <= hi; e += 8) {
        int s0 = __builtin_nontemporal_load(&src_sorted[e + 0]);
        int s1 = __builtin_nontemporal_load(&src_sorted[e + 1]);
        int s2 = __builtin_nontemporal_load(&src_sorted[e + 2]);
        int s3 = __builtin_nontemporal_load(&src_sorted[e + 3]);
        int s4 = __builtin_nontemporal_load(&src_sorted[e + 4]);
        int s5 = __builtin_nontemporal_load(&src_sorted[e + 5]);
        int s6 = __builtin_nontemporal_load(&src_sorted[e + 6]);
        int s7 = __builtin_nontemporal_load(&src_sorted[e + 7]);
        unsigned int w0 = hsb[(size_t)s0 * 64 + c];
        unsigned int w1 = hsb[(size_t)s1 * 64 + c];
        unsigned int w2 = hsb[(size_t)s2 * 64 + c];
        unsigned int w3 = hsb[(size_t)s3 * 64 + c];
        unsigned int w4 = hsb[(size_t)s4 * 64 + c];
        unsigned int w5 = hsb[(size_t)s5 * 64 + c];
        unsigned int w6 = hsb[(size_t)s6 * 64 + c];
        unsigned int w7 = hsb[(size_t)s7 * 64 + c];
        ax += ((bf_lo(w0) + bf_lo(w1)) + (bf_lo(w2) + bf_lo(w3)))
            + ((bf_lo(w4) + bf_lo(w5)) + (bf_lo(w6) + bf_lo(w7)));
        ay += ((bf_hi(w0) + bf_hi(w1)) + (bf_hi(w2) + bf_hi(w3)))
            + ((bf_hi(w4) + bf_hi(w5)) + (bf_hi(w6) + bf_hi(w7)));
    }
    if (e + 4 <= hi) {
        int s0 = __builtin_nontemporal_load(&src_sorted[e + 0]);
        int s1 = __builtin_nontemporal_load(&src_sorted[e + 1]);
        int s2 = __builtin_nontemporal_load(&src_sorted[e + 2]);
        int s3 = __builtin_nontemporal_load(&src_sorted[e + 3]);
        unsigned int w0 = hsb[(size_t)s0 * 64 + c];
        unsigned int w1 = hsb[(size_t)s1 * 64 + c];
        unsigned int w2 = hsb[(size_t)s2 * 64 + c];
        unsigned int w3 = hsb[(size_t)s3 * 64 + c];
        ax += (bf_lo(w0) + bf_lo(w1)) + (bf_lo(w2) + bf_lo(w3));
        ay += (bf_hi(w0) + bf_hi(w1)) + (bf_hi(w2) + bf_hi(w3));
        e += 4;
    }
    for (; e < hi; ++e) {
        int s = __builtin_nontemporal_load(&src_sorted[e]);
        unsigned int ws = hsb[(size_t)s * 64 + c];
        ax += bf_lo(ws);
        ay += bf_hi(ws);
    }
    float di = dinv[i];
    float2 bb = *reinterpret_cast<const float2*>(&b1[2 * c]);
    float v0 = di * ax + bb.x;
    float v1 = di * ay + bb.y;
    unsigned int pv = pack_bf2(v0 > 0.f ? v0 : 0.f, v1 > 0.f ? v1 : 0.f);
    __builtin_nontemporal_store(pv, &h2b[(size_t)i * 64 + c]);
}

// out[i][2c..2c+1] = dinv[i]*(zsb_sum) + b2; 2 nodes per 64-thread block.
__global__ __launch_bounds__(64) void k_agg2(const unsigned int* __restrict__ zsb,
                                             const float* __restrict__ dinv,
                                             const int* __restrict__ row_ptr,
                                             const int* __restrict__ src_sorted,
                                             const float* __restrict__ b2,
                                             float* __restrict__ out, int n) {
    int i = blockIdx.x * 2 + (threadIdx.x >> 5);
    int c = threadIdx.x & 31;
    if (i >= n) return;
    unsigned int w = zsb[(size_t)i * 32 + c];
    float ax = bf_lo(w), ay = bf_hi(w);
    int lo = row_ptr[i], hi = row_ptr[i + 1];
    int e = lo;
    for (; e + 8 <= hi; e += 8) {
        int s0 = __builtin_nontemporal_load(&src_sorted[e + 0]);
        int s1 = __builtin_nontemporal_load(&src_sorted[e + 1]);
        int s2 = __builtin_nontemporal_load(&src_sorted[e + 2]);
        int s3 = __builtin_nontemporal_load(&src_sorted[e + 3]);
        int s4 = __builtin_nontemporal_load(&src_sorted[e + 4]);
        int s5 = __builtin_nontemporal_load(&src_sorted[e + 5]);
        int s6 = __builtin_nontemporal_load(&src_sorted[e + 6]);
        int s7 = __builtin_nontemporal_load(&src_sorted[e + 7]);
        unsigned int w0 = zsb[(size_t)s0 * 32 + c];
        unsigned int w1 = zsb[(size_t)s1 * 32 + c];
        unsigned int w2 = zsb[(size_t)s2 * 32 + c];
        unsigned int w3 = zsb[(size_t)s3 * 32 + c];
        unsigned int w4 = zsb[(size_t)s4 * 32 + c];
        unsigned int w5 = zsb[(size_t)s5 * 32 + c];
        unsigned int w6 = zsb[(size_t)s6 * 32 + c];
        unsigned int w7 = zsb[(size_t)s7 * 32 + c];
        ax += ((bf_lo(w0) + bf_lo(w1)) + (bf_lo(w2) + bf_lo(w3)))
            + ((bf_lo(w4) + bf_lo(w5)) + (bf_lo(w6) + bf_lo(w7)));
        ay += ((bf_hi(w0) + bf_hi(w1)) + (bf_hi(w2) + bf_hi(w3)))
            + ((bf_hi(w4) + bf_hi(w5)) + (bf_hi(w6) + bf_hi(w7)));
    }
    if (e + 4 <= hi) {
        int s0 = __builtin_nontemporal_load(&src_sorted[e + 0]);
        int s1 = __builtin_nontemporal_load(&src_sorted[e + 1]);
        int s2 = __builtin_nontemporal_load(&src_sorted[e + 2]);
        int s3 = __builtin_nontemporal_load(&src_sorted[e + 3]);
        unsigned int w0 = zsb[(size_t)s0 * 32 + c];
        unsigned int w1 = zsb[(size_t)s1 * 32 + c];
        unsigned int w2 = zsb[(size_t)s2 * 32 + c];
        unsigned int w3 = zsb[(size_t)s3 * 32 + c];
        ax += (bf_lo(w0) + bf_lo(w1)) + (bf_lo(w2) + bf_lo(w3));
        ay += (bf_hi(w0) + bf_hi(w1)) + (bf_hi(w2) + bf_hi(w3));
        e += 4;
    }
    for (; e < hi; ++e) {
        int s = __builtin_nontemporal_load(&src_sorted[e]);
        unsigned int ws = zsb[(size_t)s * 32 + c];
        ax += bf_lo(ws);
        ay += bf_hi(ws);
    }
    float di = dinv[i];
    float2 bb = *reinterpret_cast<const float2*>(&b2[2 * c]);
    float2 o = {di * ax + bb.x, di * ay + bb.y};
    *reinterpret_cast<float2*>(&out[(size_t)i * 64 + 2 * c]) = o;
}

// ---------------- launch ----------------

static inline size_t alignup(size_t v) { return (v + 255) & ~(size_t)255; }

extern "C" void kernel_launch(void* const* d_in, const int* in_sizes, int n_in,
                              void* d_out, int out_size, void* d_ws, size_t ws_size,
                              hipStream_t stream) {
    const float* x  = (const float*)d_in[0];
    const void*  ei = d_in[1];
    const float* W1 = (const float*)d_in[2];
    const float* b1 = (const float*)d_in[3];
    const float* W2 = (const float*)d_in[4];
    const float* b2 = (const float*)d_in[5];

    const int n = in_sizes[0] / 128;   // 100000
    const int e = in_sizes[1] / 2;     // 3200000

    const int nb_bkt  = (n + 255) >> 8;             // 391 buckets of 256 nodes
    const int nb_chnk = (e + BKT_CH - 1) / BKT_CH;

    // Slot region (nb_bkt * BKT_CAP u32) is dead before k_gemm128 writes hsb
    // (stream-ordered) -> shares a region with hsb.
    char* p = (char*)d_ws;
    auto take = [&](size_t bytes) { char* q = p; p += alignup(bytes); return q; };
    size_t slots_bytes = (size_t)nb_bkt * BKT_CAP * 4;   // 25.6 MB
    size_t hsb_bytes   = (size_t)n * 64 * 4;             // 25.6 MB
    size_t regA_bytes  = slots_bytes > hsb_bytes ? slots_bytes : hsb_bytes;
    char* regA = (char*)take(regA_bytes);
    unsigned int* pairs = (unsigned int*)regA;
    unsigned int* hsb   = (unsigned int*)regA;

    unsigned int* h2b        = (unsigned int*)take((size_t)n * 64 * 4);
    int*          is64       = (int*)  take(4);
    float*        dinv       = (float*)take((size_t)n * 4);
    int*          row_ptr    = (int*)  take((size_t)(n + 1) * 4);
    int*          bkt_base   = (int*)  take(513 * 4);
    int*          bkt_cursor = (int*)  take(512 * 4);
    int*          src_sorted = (int*)  take((size_t)e * 4);
    unsigned int* zsb        = (unsigned int*)take((size_t)n * 32 * 4);
    if ((size_t)(p - (char*)d_ws) > ws_size) return;

    k_detect64<<<1, 256, 0, stream>>>((const unsigned int*)ei, e, is64);
    k_init_cursor<<<1, 512, 0, stream>>>(bkt_cursor);
    k_bucket_direct<<<nb_chnk, 256, 0, stream>>>(ei, e, is64, bkt_cursor, pairs);
    k_scan_bkt<<<1, 512, 0, stream>>>(bkt_cursor, bkt_base, nb_bkt);
    k_place_deg<<<nb_bkt, 256, 0, stream>>>(pairs, bkt_base, bkt_cursor, n, nb_bkt,
                                            row_ptr, dinv, src_sorted);

    k_gemm128<<<(n + 63) / 64, 256, 0, stream>>>(x, W1, dinv, hsb, n);
    k_agg1<<<n, 64, 0, stream>>>(hsb, dinv, row_ptr, src_sorted, b1, h2b);
    k_gemm64<<<(n + 63) / 64, 256, 0, stream>>>(h2b, W2, dinv, zsb, n);
    k_agg2<<<(n + 1) / 2, 64, 0, stream>>>(zsb, dinv, row_ptr, src_sorted, b2, (float*)d_out, n);
}